// Round 1
// baseline (736.862 us; speedup 1.0000x reference)
//
#include <hip/hip_runtime.h>
#include <hip/hip_bf16.h>
#include <math.h>

#define BROWS 32768
#define NNB   8
#define DIN   256
#define DH    512
#define DOUT  256
#define MTILE 64
#define CH    32
#define NCHUNK 16
#define SA    264   // xn / w1 LDS row stride (shorts): 256+8 pad -> conflict-free b128 reads
#define SH    40    // h / w2 LDS row stride (shorts): 32+8 pad

typedef __attribute__((ext_vector_type(8))) short bfrag;   // 8 x bf16 (as raw shorts)
typedef __attribute__((ext_vector_type(4))) float ffrag;   // MFMA accumulator
typedef __attribute__((ext_vector_type(4))) short s4v;

__device__ __forceinline__ short f2bf(float f) {
    union { float f; unsigned u; } v; v.f = f;
    unsigned r = v.u + 0x7fffu + ((v.u >> 16) & 1u);   // RNE
    return (short)(r >> 16);
}

// Transpose + cast weights to bf16 once per launch.
// w1t[n][k] = W1[k][n]  (n<512, k<256);  w2t[n][k] = W2[k][n]  (n<256, k<512)
__global__ void prep_weights(const float* __restrict__ W1, const float* __restrict__ W2,
                             short* __restrict__ w1t, short* __restrict__ w2t) {
    int idx = blockIdx.x * 256 + threadIdx.x;            // 0..131071
    { int n = idx >> 8, k = idx & 255; w1t[idx] = f2bf(W1[(size_t)k * DH + n]); }
    { int n = idx >> 9, k = idx & 511; w2t[idx] = f2bf(W2[(size_t)k * DOUT + n]); }
}

__global__ __launch_bounds__(256, 2)
void fused_node(const float* __restrict__ state, const float* __restrict__ nbr,
                const float* __restrict__ gamma, const float* __restrict__ beta,
                const float* __restrict__ b1g, const float* __restrict__ b2g,
                const float* __restrict__ awg, const float* __restrict__ abg,
                const short* __restrict__ w1t, const short* __restrict__ w2t,
                float* __restrict__ out) {
    __shared__ short xn_lds[MTILE * SA];    // 33792 B  LN'd input tile, bf16
    __shared__ short w1_lds[CH * SA];       // 16896 B  W1^T chunk [32 n][256 k]
    __shared__ short w2_lds[DOUT * SH];     // 20480 B  W2^T chunk [256 n][32 k]
    __shared__ short h_lds[MTILE * SH];     //  5120 B  relu(h) chunk [64 m][32 k]
    __shared__ float g_lds[DIN], bt_lds[DIN];
    __shared__ float scorep[4 * MTILE];
    __shared__ float m_lds[MTILE], l_lds[MTILE], al_lds[MTILE], pp_lds[MTILE], il_lds[MTILE];
    // total ~80.6 KB -> 2 blocks/CU

    const int tid = threadIdx.x;
    const int wv = tid >> 6, lane = tid & 63;
    const int q = lane >> 4, l16 = lane & 15;
    const int row0 = blockIdx.x * MTILE;
    const int cb = wv * 64;                  // this wave's output-column base

    g_lds[tid] = gamma[tid];
    bt_lds[tid] = beta[tid];
    if (tid < MTILE) { m_lds[tid] = -__builtin_huge_valf(); l_lds[tid] = 0.f; }

    float b2v[4], awv[4];
    #pragma unroll
    for (int ct = 0; ct < 4; ++ct) {
        int col = cb + ct * 16 + l16;
        b2v[ct] = b2g[col];
        awv[ct] = awg[col];
    }
    const float attnb = abg[0];

    ffrag agg[4][4];
    #pragma unroll
    for (int mt = 0; mt < 4; ++mt)
        #pragma unroll
        for (int ct = 0; ct < 4; ++ct) {
            ffrag z = {0.f, 0.f, 0.f, 0.f};
            agg[mt][ct] = z;
        }

    ffrag feat[4][4];

    // sets 0..7 = neighbors (online softmax into agg), set 8 = local state
    for (int s = 0; s < 9; ++s) {
        const bool loc = (s == 8);
        const float* xb = loc ? (state + (size_t)row0 * DIN)
                              : (nbr + ((size_t)s * BROWS + (size_t)row0) * DIN);
        __syncthreads();   // prior reads of xn_lds done; init visible on s==0
        // ---- LayerNorm (fp32) -> bf16 tile ----
        {
            const int r = tid >> 2, qq = tid & 3;     // 4 threads per row
            const float* src = xb + r * DIN + qq * 64;
            float4 v[16];
            float sum = 0.f, ssq = 0.f;
            #pragma unroll
            for (int i = 0; i < 16; ++i) {
                v[i] = ((const float4*)src)[i];
                sum += v[i].x + v[i].y + v[i].z + v[i].w;
                ssq += v[i].x * v[i].x + v[i].y * v[i].y + v[i].z * v[i].z + v[i].w * v[i].w;
            }
            sum += __shfl_xor(sum, 1); sum += __shfl_xor(sum, 2);
            ssq += __shfl_xor(ssq, 1); ssq += __shfl_xor(ssq, 2);
            float mean = sum * (1.f / 256.f);
            float var = ssq * (1.f / 256.f) - mean * mean;
            float rstd = rsqrtf(var + 1e-5f);
            short* dst = xn_lds + r * SA + qq * 64;
            #pragma unroll
            for (int i = 0; i < 16; ++i) {
                int c = qq * 64 + i * 4;
                s4v t;
                t.x = f2bf((v[i].x - mean) * rstd * g_lds[c + 0] + bt_lds[c + 0]);
                t.y = f2bf((v[i].y - mean) * rstd * g_lds[c + 1] + bt_lds[c + 1]);
                t.z = f2bf((v[i].z - mean) * rstd * g_lds[c + 2] + bt_lds[c + 2]);
                t.w = f2bf((v[i].w - mean) * rstd * g_lds[c + 3] + bt_lds[c + 3]);
                *(s4v*)(dst + i * 4) = t;
            }
        }
        // init feat accumulators with b2 broadcast (all 4 regs of a C-tile share one column)
        #pragma unroll
        for (int mt = 0; mt < 4; ++mt)
            #pragma unroll
            for (int ct = 0; ct < 4; ++ct) {
                ffrag fi = {b2v[ct], b2v[ct], b2v[ct], b2v[ct]};
                feat[mt][ct] = fi;
            }

        for (int c = 0; c < NCHUNK; ++c) {
            __syncthreads();   // prior stage2 reads of w2/h done; xn visible (c==0)
            // ---- stage weight chunks into LDS ----
            {
                const short* s1 = w1t + c * CH * DIN;          // 32 contiguous rows of 256
                #pragma unroll
                for (int i = 0; i < 4; ++i) {
                    int f = tid + 256 * i;
                    int rr = f >> 5, c8 = f & 31;
                    *(bfrag*)(w1_lds + rr * SA + c8 * 8) = *(const bfrag*)(s1 + f * 8);
                }
                const short* s2 = w2t + c * CH;                // 256 rows, 32-col slice
                #pragma unroll
                for (int i = 0; i < 4; ++i) {
                    int f = tid + 256 * i;
                    int rr = f >> 2, c8 = f & 3;
                    *(bfrag*)(w2_lds + rr * SH + c8 * 8) = *(const bfrag*)(s2 + rr * DH + c8 * 8);
                }
            }
            __syncthreads();
            // ---- stage 1: h = xn @ W1[:,chunk] + b1, relu, -> LDS (wave wv owns rows 16wv..16wv+16)
            {
                float bb0 = b1g[c * CH + l16], bb1 = b1g[c * CH + 16 + l16];
                ffrag h0 = {bb0, bb0, bb0, bb0};
                ffrag h1 = {bb1, bb1, bb1, bb1};
                const short* ap  = xn_lds + (wv * 16 + l16) * SA + q * 8;
                const short* bp0 = w1_lds + l16 * SA + q * 8;
                const short* bp1 = w1_lds + (16 + l16) * SA + q * 8;
                #pragma unroll
                for (int kb = 0; kb < 8; ++kb) {
                    bfrag a  = *(const bfrag*)(ap + kb * 32);
                    bfrag v0 = *(const bfrag*)(bp0 + kb * 32);
                    bfrag v1 = *(const bfrag*)(bp1 + kb * 32);
                    h0 = __builtin_amdgcn_mfma_f32_16x16x32_bf16(a, v0, h0, 0, 0, 0);
                    h1 = __builtin_amdgcn_mfma_f32_16x16x32_bf16(a, v1, h1, 0, 0, 0);
                }
                short* hb = h_lds + (wv * 16 + q * 4) * SH + l16;   // C layout: row=q*4+r, col=l16
                #pragma unroll
                for (int r = 0; r < 4; ++r) {
                    hb[r * SH]      = f2bf(fmaxf(h0[r], 0.f));
                    hb[r * SH + 16] = f2bf(fmaxf(h1[r], 0.f));
                }
            }
            __syncthreads();
            // ---- stage 2: feat += relu(h) @ W2[chunk,:]  (wave wv owns cols cb..cb+64)
            {
                bfrag af[4], bf[4];
                #pragma unroll
                for (int mt = 0; mt < 4; ++mt)
                    af[mt] = *(const bfrag*)(h_lds + (mt * 16 + l16) * SH + q * 8);
                #pragma unroll
                for (int ct = 0; ct < 4; ++ct)
                    bf[ct] = *(const bfrag*)(w2_lds + (cb + ct * 16 + l16) * SH + q * 8);
                #pragma unroll
                for (int mt = 0; mt < 4; ++mt)
                    #pragma unroll
                    for (int ct = 0; ct < 4; ++ct)
                        feat[mt][ct] = __builtin_amdgcn_mfma_f32_16x16x32_bf16(af[mt], bf[ct], feat[mt][ct], 0, 0, 0);
            }
        }

        if (!loc) {
            // ---- score = feat . attn_w + attn_b, online softmax over neighbors ----
            float sp[4][4];
            #pragma unroll
            for (int mt = 0; mt < 4; ++mt)
                #pragma unroll
                for (int r = 0; r < 4; ++r) {
                    float vv = feat[mt][0][r] * awv[0] + feat[mt][1][r] * awv[1]
                             + feat[mt][2][r] * awv[2] + feat[mt][3][r] * awv[3];
                    vv += __shfl_xor(vv, 1); vv += __shfl_xor(vv, 2);
                    vv += __shfl_xor(vv, 4); vv += __shfl_xor(vv, 8);
                    sp[mt][r] = vv;       // full sum over this wave's 64 cols, rows mt*16+q*4+r
                }
            if (l16 == 0) {
                #pragma unroll
                for (int mt = 0; mt < 4; ++mt)
                    #pragma unroll
                    for (int r = 0; r < 4; ++r)
                        scorep[wv * MTILE + mt * 16 + q * 4 + r] = sp[mt][r];
            }
            __syncthreads();
            if (tid < MTILE) {
                float sc = scorep[tid] + scorep[MTILE + tid] + scorep[2 * MTILE + tid]
                         + scorep[3 * MTILE + tid] + attnb;
                float mo = m_lds[tid];
                float mn = fmaxf(mo, sc);
                float al = __expf(mo - mn);     // exp(-inf)=0 on first neighbor
                float pp = __expf(sc - mn);
                float ln = l_lds[tid] * al + pp;
                m_lds[tid] = mn; l_lds[tid] = ln;
                al_lds[tid] = al; pp_lds[tid] = pp;
                if (s == NNB - 1) il_lds[tid] = 1.f / ln;
            }
            __syncthreads();
            #pragma unroll
            for (int mt = 0; mt < 4; ++mt) {
                float alv[4], ppv[4];
                #pragma unroll
                for (int r = 0; r < 4; ++r) {
                    int rr = mt * 16 + q * 4 + r;
                    alv[r] = al_lds[rr]; ppv[r] = pp_lds[rr];
                }
                #pragma unroll
                for (int ct = 0; ct < 4; ++ct)
                    #pragma unroll
                    for (int r = 0; r < 4; ++r)
                        agg[mt][ct][r] = agg[mt][ct][r] * alv[r] + ppv[r] * feat[mt][ct][r];
            }
        }
    }

    // ---- out = local_feat + agg / l ----
    #pragma unroll
    for (int mt = 0; mt < 4; ++mt)
        #pragma unroll
        for (int r = 0; r < 4; ++r) {
            int rr = mt * 16 + q * 4 + r;
            float il = il_lds[rr];
            size_t base = (size_t)(row0 + rr) * DOUT + cb + l16;
            #pragma unroll
            for (int ct = 0; ct < 4; ++ct)
                out[base + ct * 16] = feat[mt][ct][r] + agg[mt][ct][r] * il;
        }
}

extern "C" void kernel_launch(void* const* d_in, const int* in_sizes, int n_in,
                              void* d_out, int out_size, void* d_ws, size_t ws_size,
                              hipStream_t stream) {
    const float* state = (const float*)d_in[0];
    const float* nbr   = (const float*)d_in[1];
    const float* gamma = (const float*)d_in[2];
    const float* beta  = (const float*)d_in[3];
    const float* W1    = (const float*)d_in[4];
    const float* b1    = (const float*)d_in[5];
    const float* W2    = (const float*)d_in[6];
    const float* b2    = (const float*)d_in[7];
    const float* aw    = (const float*)d_in[8];
    const float* ab    = (const float*)d_in[9];
    float* out = (float*)d_out;

    short* w1t = (short*)d_ws;              // [512][256] bf16
    short* w2t = w1t + (size_t)DH * DIN;    // [256][512] bf16  (total 512 KB of ws)

    prep_weights<<<512, 256, 0, stream>>>(W1, W2, w1t, w2t);
    fused_node<<<BROWS / MTILE, 256, 0, stream>>>(state, nbr, gamma, beta,
                                                  b1, b2, aw, ab, w1t, w2t, out);
}

// Round 2
// 723.243 us; speedup vs baseline: 1.0188x; 1.0188x over previous
//
#include <hip/hip_runtime.h>
#include <hip/hip_bf16.h>
#include <math.h>

#define BROWS 32768
#define NNB   8
#define DIN   256
#define DH    512
#define DOUT  256
#define MTILE 64
#define CH    32
#define NCHUNK 16
#define SA    264   // xn / w1 LDS row stride (shorts): 256+8 pad -> conflict-free b128 reads
#define SH    40    // h / w2 LDS row stride (shorts): 32+8 pad

typedef __attribute__((ext_vector_type(8))) short bfrag;   // 8 x bf16 (as raw shorts)
typedef __attribute__((ext_vector_type(4))) float ffrag;   // MFMA accumulator
typedef __attribute__((ext_vector_type(4))) short s4v;

__device__ __forceinline__ short f2bf(float f) {
    union { float f; unsigned u; } v; v.f = f;
    unsigned r = v.u + 0x7fffu + ((v.u >> 16) & 1u);   // RNE
    return (short)(r >> 16);
}

// Coalesced transpose + cast: dst[c][r] = bf16(src[r][c]), src is R x C fp32.
// grid = (C/64, R/64), block = 256.
__global__ void tcast(const float* __restrict__ src, short* __restrict__ dst,
                      int R, int C) {
    __shared__ short t[64][67];   // odd-ish stride: transpose reads ~conflict-light
    const int c0 = blockIdx.x * 64, r0 = blockIdx.y * 64;
    const int lr = threadIdx.x >> 6, lc = threadIdx.x & 63;
    #pragma unroll
    for (int i = 0; i < 16; ++i) {
        int row = i * 4 + lr;
        t[row][lc] = f2bf(src[(size_t)(r0 + row) * C + c0 + lc]);  // coalesced read
    }
    __syncthreads();
    #pragma unroll
    for (int i = 0; i < 16; ++i) {
        int row = i * 4 + lr;
        dst[(size_t)(c0 + row) * R + r0 + lc] = t[lc][row];        // coalesced write
    }
}

__global__ __launch_bounds__(256, 2)
void fused_node(const float* __restrict__ state, const float* __restrict__ nbr,
                const float* __restrict__ gamma, const float* __restrict__ beta,
                const float* __restrict__ b1g, const float* __restrict__ b2g,
                const float* __restrict__ awg, const float* __restrict__ abg,
                const short* __restrict__ w1t, const short* __restrict__ w2t,
                float* __restrict__ out) {
    __shared__ short xn_lds[MTILE * SA];    // 33792 B  LN'd input tile, bf16
    __shared__ short w1_lds[CH * SA];       // 16896 B  W1^T chunk [32 n][256 k]
    __shared__ short w2_lds[DOUT * SH];     // 20480 B  W2^T chunk [256 n][32 k]
    __shared__ short h_lds[MTILE * SH];     //  5120 B  relu(h) chunk [64 m][32 k]
    __shared__ float g_lds[DIN], bt_lds[DIN];
    __shared__ float scorep[4 * MTILE];
    __shared__ float m_lds[MTILE], l_lds[MTILE], al_lds[MTILE], pp_lds[MTILE], il_lds[MTILE];
    // total ~80.6 KB -> 2 blocks/CU

    const int tid = threadIdx.x;
    const int wv = tid >> 6, lane = tid & 63;
    const int q = lane >> 4, l16 = lane & 15;
    const int row0 = blockIdx.x * MTILE;
    const int cb = wv * 64;                  // this wave's output-column base

    g_lds[tid] = gamma[tid];
    bt_lds[tid] = beta[tid];
    if (tid < MTILE) { m_lds[tid] = -__builtin_huge_valf(); l_lds[tid] = 0.f; }

    float b2v[4], awv[4];
    #pragma unroll
    for (int ct = 0; ct < 4; ++ct) {
        int col = cb + ct * 16 + l16;
        b2v[ct] = b2g[col];
        awv[ct] = awg[col];
    }
    const float attnb = abg[0];

    ffrag agg[4][4];
    #pragma unroll
    for (int mt = 0; mt < 4; ++mt)
        #pragma unroll
        for (int ct = 0; ct < 4; ++ct) {
            ffrag z = {0.f, 0.f, 0.f, 0.f};
            agg[mt][ct] = z;
        }

    ffrag feat[4][4];

    // sets 0..7 = neighbors (online softmax into agg), set 8 = local state
    for (int s = 0; s < 9; ++s) {
        const bool loc = (s == 8);
        const float* xb = loc ? (state + (size_t)row0 * DIN)
                              : (nbr + ((size_t)s * BROWS + (size_t)row0) * DIN);
        __syncthreads();   // prior reads of xn_lds done; init visible on s==0
        // ---- LayerNorm (fp32), two-pass to avoid any register-array spill ----
        {
            const int r = tid >> 2, qq = tid & 3;     // 4 threads per row, 64 floats each
            const float* src = xb + r * DIN + qq * 64;
            // pass 1: stream sums (loads die immediately into accumulators)
            float s0 = 0.f, s1 = 0.f, q0 = 0.f, q1 = 0.f;
            #pragma unroll
            for (int i = 0; i < 16; ++i) {
                float4 v = ((const float4*)src)[i];
                s0 += v.x + v.y;
                s1 += v.z + v.w;
                q0 = fmaf(v.x, v.x, fmaf(v.y, v.y, q0));
                q1 = fmaf(v.z, v.z, fmaf(v.w, v.w, q1));
            }
            float sum = s0 + s1, ssq = q0 + q1;
            sum += __shfl_xor(sum, 1); sum += __shfl_xor(sum, 2);
            ssq += __shfl_xor(ssq, 1); ssq += __shfl_xor(ssq, 2);
            float mean = sum * (1.f / 256.f);
            float var = ssq * (1.f / 256.f) - mean * mean;
            float rstd = rsqrtf(var + 1e-5f);
            // pass 2: re-read (L1/L2 hit), normalize, pack bf16 -> LDS
            short* dst = xn_lds + r * SA + qq * 64;
            #pragma unroll
            for (int i = 0; i < 16; ++i) {
                float4 v = ((const float4*)src)[i];
                int c = qq * 64 + i * 4;
                float4 g4 = *(const float4*)(g_lds + c);
                float4 t4 = *(const float4*)(bt_lds + c);
                s4v t;
                t.x = f2bf(fmaf((v.x - mean) * rstd, g4.x, t4.x));
                t.y = f2bf(fmaf((v.y - mean) * rstd, g4.y, t4.y));
                t.z = f2bf(fmaf((v.z - mean) * rstd, g4.z, t4.z));
                t.w = f2bf(fmaf((v.w - mean) * rstd, g4.w, t4.w));
                *(s4v*)(dst + i * 4) = t;
            }
        }
        // init feat accumulators with b2 broadcast (all 4 regs of a C-tile share one column)
        #pragma unroll
        for (int mt = 0; mt < 4; ++mt)
            #pragma unroll
            for (int ct = 0; ct < 4; ++ct) {
                ffrag fi = {b2v[ct], b2v[ct], b2v[ct], b2v[ct]};
                feat[mt][ct] = fi;
            }

        for (int c = 0; c < NCHUNK; ++c) {
            __syncthreads();   // prior stage2 reads of w2/h done; xn visible (c==0)
            // ---- stage weight chunks into LDS ----
            {
                const short* s1 = w1t + c * CH * DIN;          // 32 contiguous rows of 256
                #pragma unroll
                for (int i = 0; i < 4; ++i) {
                    int f = tid + 256 * i;
                    int rr = f >> 5, c8 = f & 31;
                    *(bfrag*)(w1_lds + rr * SA + c8 * 8) = *(const bfrag*)(s1 + f * 8);
                }
                const short* s2 = w2t + c * CH;                // 256 rows, 32-col slice
                #pragma unroll
                for (int i = 0; i < 4; ++i) {
                    int f = tid + 256 * i;
                    int rr = f >> 2, c8 = f & 3;
                    *(bfrag*)(w2_lds + rr * SH + c8 * 8) = *(const bfrag*)(s2 + rr * DH + c8 * 8);
                }
            }
            __syncthreads();
            // ---- stage 1: h = xn @ W1[:,chunk] + b1, relu, -> LDS (wave wv owns rows 16wv..16wv+16)
            {
                float bb0 = b1g[c * CH + l16], bb1 = b1g[c * CH + 16 + l16];
                ffrag h0 = {bb0, bb0, bb0, bb0};
                ffrag h1 = {bb1, bb1, bb1, bb1};
                const short* ap  = xn_lds + (wv * 16 + l16) * SA + q * 8;
                const short* bp0 = w1_lds + l16 * SA + q * 8;
                const short* bp1 = w1_lds + (16 + l16) * SA + q * 8;
                #pragma unroll
                for (int kb = 0; kb < 8; ++kb) {
                    bfrag a  = *(const bfrag*)(ap + kb * 32);
                    bfrag v0 = *(const bfrag*)(bp0 + kb * 32);
                    bfrag v1 = *(const bfrag*)(bp1 + kb * 32);
                    h0 = __builtin_amdgcn_mfma_f32_16x16x32_bf16(a, v0, h0, 0, 0, 0);
                    h1 = __builtin_amdgcn_mfma_f32_16x16x32_bf16(a, v1, h1, 0, 0, 0);
                }
                short* hb = h_lds + (wv * 16 + q * 4) * SH + l16;   // C layout: row=q*4+r, col=l16
                #pragma unroll
                for (int r = 0; r < 4; ++r) {
                    hb[r * SH]      = f2bf(fmaxf(h0[r], 0.f));
                    hb[r * SH + 16] = f2bf(fmaxf(h1[r], 0.f));
                }
            }
            __syncthreads();
            // ---- stage 2: feat += relu(h) @ W2[chunk,:]  (wave wv owns cols cb..cb+64)
            {
                bfrag af[4], bf[4];
                #pragma unroll
                for (int mt = 0; mt < 4; ++mt)
                    af[mt] = *(const bfrag*)(h_lds + (mt * 16 + l16) * SH + q * 8);
                #pragma unroll
                for (int ct = 0; ct < 4; ++ct)
                    bf[ct] = *(const bfrag*)(w2_lds + (cb + ct * 16 + l16) * SH + q * 8);
                #pragma unroll
                for (int mt = 0; mt < 4; ++mt)
                    #pragma unroll
                    for (int ct = 0; ct < 4; ++ct)
                        feat[mt][ct] = __builtin_amdgcn_mfma_f32_16x16x32_bf16(af[mt], bf[ct], feat[mt][ct], 0, 0, 0);
            }
        }

        if (!loc) {
            // ---- score = feat . attn_w + attn_b, online softmax over neighbors ----
            float sp[4][4];
            #pragma unroll
            for (int mt = 0; mt < 4; ++mt)
                #pragma unroll
                for (int r = 0; r < 4; ++r) {
                    float vv = feat[mt][0][r] * awv[0] + feat[mt][1][r] * awv[1]
                             + feat[mt][2][r] * awv[2] + feat[mt][3][r] * awv[3];
                    vv += __shfl_xor(vv, 1); vv += __shfl_xor(vv, 2);
                    vv += __shfl_xor(vv, 4); vv += __shfl_xor(vv, 8);
                    sp[mt][r] = vv;       // full sum over this wave's 64 cols, rows mt*16+q*4+r
                }
            if (l16 == 0) {
                #pragma unroll
                for (int mt = 0; mt < 4; ++mt)
                    #pragma unroll
                    for (int r = 0; r < 4; ++r)
                        scorep[wv * MTILE + mt * 16 + q * 4 + r] = sp[mt][r];
            }
            __syncthreads();
            if (tid < MTILE) {
                float sc = scorep[tid] + scorep[MTILE + tid] + scorep[2 * MTILE + tid]
                         + scorep[3 * MTILE + tid] + attnb;
                float mo = m_lds[tid];
                float mn = fmaxf(mo, sc);
                float al = __expf(mo - mn);     // exp(-inf)=0 on first neighbor
                float pp = __expf(sc - mn);
                float ln = l_lds[tid] * al + pp;
                m_lds[tid] = mn; l_lds[tid] = ln;
                al_lds[tid] = al; pp_lds[tid] = pp;
                if (s == NNB - 1) il_lds[tid] = 1.f / ln;
            }
            __syncthreads();
            #pragma unroll
            for (int mt = 0; mt < 4; ++mt) {
                float alv[4], ppv[4];
                #pragma unroll
                for (int r = 0; r < 4; ++r) {
                    int rr = mt * 16 + q * 4 + r;
                    alv[r] = al_lds[rr]; ppv[r] = pp_lds[rr];
                }
                #pragma unroll
                for (int ct = 0; ct < 4; ++ct)
                    #pragma unroll
                    for (int r = 0; r < 4; ++r)
                        agg[mt][ct][r] = agg[mt][ct][r] * alv[r] + ppv[r] * feat[mt][ct][r];
            }
        }
    }

    // ---- out = local_feat + agg / l ----
    #pragma unroll
    for (int mt = 0; mt < 4; ++mt)
        #pragma unroll
        for (int r = 0; r < 4; ++r) {
            int rr = mt * 16 + q * 4 + r;
            float il = il_lds[rr];
            size_t base = (size_t)(row0 + rr) * DOUT + cb + l16;
            #pragma unroll
            for (int ct = 0; ct < 4; ++ct)
                out[base + ct * 16] = feat[mt][ct][r] + agg[mt][ct][r] * il;
        }
}

extern "C" void kernel_launch(void* const* d_in, const int* in_sizes, int n_in,
                              void* d_out, int out_size, void* d_ws, size_t ws_size,
                              hipStream_t stream) {
    const float* state = (const float*)d_in[0];
    const float* nbr   = (const float*)d_in[1];
    const float* gamma = (const float*)d_in[2];
    const float* beta  = (const float*)d_in[3];
    const float* W1    = (const float*)d_in[4];
    const float* b1    = (const float*)d_in[5];
    const float* W2    = (const float*)d_in[6];
    const float* b2    = (const float*)d_in[7];
    const float* aw    = (const float*)d_in[8];
    const float* ab    = (const float*)d_in[9];
    float* out = (float*)d_out;

    short* w1t = (short*)d_ws;              // [512][256] bf16
    short* w2t = w1t + (size_t)DH * DIN;    // [256][512] bf16  (total 512 KB of ws)

    // W1 is 256x512 -> w1t 512x256 ; W2 is 512x256 -> w2t 256x512
    tcast<<<dim3(DH / 64, DIN / 64), 256, 0, stream>>>(W1, w1t, DIN, DH);
    tcast<<<dim3(DOUT / 64, DH / 64), 256, 0, stream>>>(W2, w2t, DH, DOUT);
    fused_node<<<BROWS / MTILE, 256, 0, stream>>>(state, nbr, gamma, beta,
                                                  b1, b2, aw, ab, w1t, w2t, out);
}

// Round 3
// 635.399 us; speedup vs baseline: 1.1597x; 1.1383x over previous
//
#include <hip/hip_runtime.h>
#include <hip/hip_bf16.h>
#include <math.h>

#define BROWS 32768
#define NNB   8
#define DIN   256
#define DH    512
#define DOUT  256
#define MROWS 128   // rows per block
#define CH    32
#define NCHUNK 16
#define SA    264   // w1 LDS row stride (shorts)
#define SH    40    // h / w2 LDS row stride (shorts)

typedef __attribute__((ext_vector_type(8))) short bfrag;   // 8 x bf16
typedef __attribute__((ext_vector_type(4))) float ffrag;   // MFMA accumulator
typedef __attribute__((ext_vector_type(4))) float f4v;

__device__ __forceinline__ short f2bf(float f) {
    union { float f; unsigned u; } v; v.f = f;
    unsigned r = v.u + 0x7fffu + ((v.u >> 16) & 1u);   // RNE
    return (short)(r >> 16);
}

// Coalesced transpose + cast with gamma fold: dst[c][r] = bf16(src[r][c]*g[r])
__global__ void tcast_g(const float* __restrict__ src, const float* __restrict__ g,
                        short* __restrict__ dst, int R, int C) {
    __shared__ short t[64][67];
    const int c0 = blockIdx.x * 64, r0 = blockIdx.y * 64;
    const int lr = threadIdx.x >> 6, lc = threadIdx.x & 63;
    #pragma unroll
    for (int i = 0; i < 16; ++i) {
        int row = i * 4 + lr;
        t[row][lc] = f2bf(src[(size_t)(r0 + row) * C + c0 + lc] * g[r0 + row]);
    }
    __syncthreads();
    #pragma unroll
    for (int i = 0; i < 16; ++i) {
        int row = i * 4 + lr;
        dst[(size_t)(c0 + row) * R + r0 + lc] = t[lc][row];
    }
}

__global__ void tcast(const float* __restrict__ src, short* __restrict__ dst,
                      int R, int C) {
    __shared__ short t[64][67];
    const int c0 = blockIdx.x * 64, r0 = blockIdx.y * 64;
    const int lr = threadIdx.x >> 6, lc = threadIdx.x & 63;
    #pragma unroll
    for (int i = 0; i < 16; ++i) {
        int row = i * 4 + lr;
        t[row][lc] = f2bf(src[(size_t)(r0 + row) * C + c0 + lc]);
    }
    __syncthreads();
    #pragma unroll
    for (int i = 0; i < 16; ++i) {
        int row = i * 4 + lr;
        dst[(size_t)(c0 + row) * R + r0 + lc] = t[lc][row];
    }
}

// b1p[n] = b1[n] + sum_k beta[k] * W1[k][n]
__global__ void b1prep(const float* __restrict__ W1, const float* __restrict__ b1,
                       const float* __restrict__ beta, float* __restrict__ b1p) {
    int n = blockIdx.x * 256 + threadIdx.x;
    float acc = b1[n];
    for (int k = 0; k < DIN; ++k) acc += beta[k] * W1[(size_t)k * DH + n];
    b1p[n] = acc;
}

__global__ __launch_bounds__(512, 2)
void fused_node(const float* __restrict__ state, const float* __restrict__ nbr,
                const float* __restrict__ b1p, const float* __restrict__ b2g,
                const float* __restrict__ awg, const float* __restrict__ abg,
                const short* __restrict__ w1t, const short* __restrict__ w2t,
                float* __restrict__ out) {
    __shared__ short w1_lds[2][CH * SA];     // 2 x 16896 B
    __shared__ short w2_lds[2][DOUT * SH];   // 2 x 20480 B
    __shared__ short h_lds[MROWS * SH];      // 10240 B
    __shared__ float b1_lds[DH];             // 2048 B
    __shared__ float scorep[4 * MROWS];      // 2048 B
    __shared__ float m_lds[MROWS], l_lds[MROWS], al_lds[MROWS], pp_lds[MROWS], il_lds[MROWS];
    // total ~91.6 KB -> 1 block/CU, 8 waves

    const int tid = threadIdx.x;
    const int wv = tid >> 6, lane = tid & 63;
    const int q = lane >> 4, l16 = lane & 15;
    const int rg = wv >> 2, cg = wv & 3;       // stage2 wave grid: 2 row x 4 col
    const int row0 = blockIdx.x * MROWS;
    const int myrow = 16 * wv + l16;           // stage1/LN row owned by this thread

    // staging index precompute (f0 = tid, f1 = tid+512)
    const int f0 = tid, f1 = tid + 512;
    const int w1r0 = f0 >> 5, w1c0 = f0 & 31, w1r1 = f1 >> 5, w1c1 = f1 & 31;
    const int w2r0 = f0 >> 2, w2c0 = f0 & 3,  w2r1 = f1 >> 2, w2c1 = f1 & 3;

    // ---- prologue: issue chunk-0 weight loads, stage b1p, init softmax state ----
    bfrag L1a = *(const bfrag*)(w1t + (size_t)f0 * 8);
    bfrag L1b = *(const bfrag*)(w1t + (size_t)f1 * 8);
    bfrag L2a = *(const bfrag*)(w2t + (size_t)w2r0 * DH + w2c0 * 8);
    bfrag L2b = *(const bfrag*)(w2t + (size_t)w2r1 * DH + w2c1 * 8);
    if (tid < DH) b1_lds[tid] = b1p[tid];
    if (tid < MROWS) { m_lds[tid] = -__builtin_huge_valf(); l_lds[tid] = 0.f; }
    *(bfrag*)(&w1_lds[0][w1r0 * SA + w1c0 * 8]) = L1a;
    *(bfrag*)(&w1_lds[0][w1r1 * SA + w1c1 * 8]) = L1b;
    *(bfrag*)(&w2_lds[0][w2r0 * SH + w2c0 * 8]) = L2a;
    *(bfrag*)(&w2_lds[0][w2r1 * SH + w2c1 * 8]) = L2b;

    float b2v[4], awv[4];
    #pragma unroll
    for (int ct = 0; ct < 4; ++ct) {
        int col = 64 * cg + 16 * ct + l16;
        b2v[ct] = b2g[col];
        awv[ct] = awg[col];
    }
    const float attnb = abg[0];

    ffrag agg[4][4];
    #pragma unroll
    for (int mt = 0; mt < 4; ++mt)
        #pragma unroll
        for (int ct = 0; ct < 4; ++ct) { ffrag z = {0.f,0.f,0.f,0.f}; agg[mt][ct] = z; }

    ffrag feat[4][4];
    bfrag xnf[8];   // LN'd row in MFMA A-fragment layout (row=myrow, k=32kb+8q+j)

    for (int s = 0; s < 9; ++s) {
        const bool loc = (s == 8);
        const float* xb = loc ? (state + (size_t)row0 * DIN)
                              : (nbr + ((size_t)s * BROWS + (size_t)row0) * DIN);
        // ---- LayerNorm fully in registers ----
        {
            const float* xr = xb + (size_t)myrow * DIN + q * 8;
            f4v xa[8], xc[8];
            #pragma unroll
            for (int kb = 0; kb < 8; ++kb) {
                xa[kb] = __builtin_nontemporal_load((const f4v*)(xr + kb * 32));
                xc[kb] = __builtin_nontemporal_load((const f4v*)(xr + kb * 32 + 4));
            }
            float sum = 0.f, ssq = 0.f;
            #pragma unroll
            for (int kb = 0; kb < 8; ++kb) {
                #pragma unroll
                for (int j = 0; j < 4; ++j) {
                    sum += xa[kb][j] + xc[kb][j];
                    ssq = fmaf(xa[kb][j], xa[kb][j], fmaf(xc[kb][j], xc[kb][j], ssq));
                }
            }
            sum += __shfl_xor(sum, 16); sum += __shfl_xor(sum, 32);
            ssq += __shfl_xor(ssq, 16); ssq += __shfl_xor(ssq, 32);
            float mean = sum * (1.f / 256.f);
            float var = ssq * (1.f / 256.f) - mean * mean;
            float rstd = rsqrtf(var + 1e-5f);
            #pragma unroll
            for (int kb = 0; kb < 8; ++kb) {
                bfrag t;
                #pragma unroll
                for (int j = 0; j < 4; ++j) {
                    t[j]     = f2bf((xa[kb][j] - mean) * rstd);
                    t[j + 4] = f2bf((xc[kb][j] - mean) * rstd);
                }
                xnf[kb] = t;
            }
        }
        // init feat with b2 broadcast
        #pragma unroll
        for (int mt = 0; mt < 4; ++mt)
            #pragma unroll
            for (int ct = 0; ct < 4; ++ct) {
                ffrag fi = {b2v[ct], b2v[ct], b2v[ct], b2v[ct]};
                feat[mt][ct] = fi;
            }

        for (int c = 0; c < NCHUNK; ++c) {
            const int p = c & 1;
            __syncthreads();   // A: buf[p] visible, h free (prev st2 done)
            // issue weight loads for next chunk (same for every set)
            const bool more = (c < NCHUNK - 1) || (s < 8);
            const int nc = (c + 1) & (NCHUNK - 1);
            if (more) {
                const short* s1 = w1t + (size_t)nc * CH * DIN;
                const short* s2 = w2t + nc * CH;
                L1a = *(const bfrag*)(s1 + (size_t)f0 * 8);
                L1b = *(const bfrag*)(s1 + (size_t)f1 * 8);
                L2a = *(const bfrag*)(s2 + (size_t)w2r0 * DH + w2c0 * 8);
                L2b = *(const bfrag*)(s2 + (size_t)w2r1 * DH + w2c1 * 8);
            }
            // ---- stage 1: h(myrow rows, 32 cols) = xn @ W1chunk + b1', relu ----
            {
                float bb0 = b1_lds[c * CH + l16], bb1 = b1_lds[c * CH + 16 + l16];
                ffrag h0 = {bb0, bb0, bb0, bb0};
                ffrag h1 = {bb1, bb1, bb1, bb1};
                const short* bp = &w1_lds[p][l16 * SA + q * 8];
                #pragma unroll
                for (int kb = 0; kb < 8; ++kb) {
                    bfrag v0 = *(const bfrag*)(bp + kb * 32);
                    bfrag v1 = *(const bfrag*)(bp + 16 * SA + kb * 32);
                    h0 = __builtin_amdgcn_mfma_f32_16x16x32_bf16(xnf[kb], v0, h0, 0, 0, 0);
                    h1 = __builtin_amdgcn_mfma_f32_16x16x32_bf16(xnf[kb], v1, h1, 0, 0, 0);
                }
                short* hb = h_lds + (16 * wv + 4 * q) * SH + l16;   // C layout: row=4q+r, col=l16
                #pragma unroll
                for (int r = 0; r < 4; ++r) {
                    hb[r * SH]      = f2bf(fmaxf(h0[r], 0.f));
                    hb[r * SH + 16] = f2bf(fmaxf(h1[r], 0.f));
                }
            }
            // park next chunk's weights into the other buffer
            if (more) {
                *(bfrag*)(&w1_lds[1 - p][w1r0 * SA + w1c0 * 8]) = L1a;
                *(bfrag*)(&w1_lds[1 - p][w1r1 * SA + w1c1 * 8]) = L1b;
                *(bfrag*)(&w2_lds[1 - p][w2r0 * SH + w2c0 * 8]) = L2a;
                *(bfrag*)(&w2_lds[1 - p][w2r1 * SH + w2c1 * 8]) = L2b;
            }
            __syncthreads();   // B: h visible (and parked weights for next iter)
            // ---- stage 2: feat += relu(h) @ W2chunk ; wave = 64 rows x 64 cols ----
            {
                bfrag af[4], bfr[4];
                #pragma unroll
                for (int mt = 0; mt < 4; ++mt)
                    af[mt] = *(const bfrag*)(h_lds + (64 * rg + 16 * mt + l16) * SH + q * 8);
                #pragma unroll
                for (int ct = 0; ct < 4; ++ct)
                    bfr[ct] = *(const bfrag*)(&w2_lds[p][(64 * cg + 16 * ct + l16) * SH + q * 8]);
                #pragma unroll
                for (int mt = 0; mt < 4; ++mt)
                    #pragma unroll
                    for (int ct = 0; ct < 4; ++ct)
                        feat[mt][ct] = __builtin_amdgcn_mfma_f32_16x16x32_bf16(af[mt], bfr[ct], feat[mt][ct], 0, 0, 0);
            }
        }

        if (!loc) {
            // ---- scores + online softmax over neighbors ----
            float sp[4][4];
            #pragma unroll
            for (int mt = 0; mt < 4; ++mt)
                #pragma unroll
                for (int r = 0; r < 4; ++r) {
                    float vv = feat[mt][0][r] * awv[0] + feat[mt][1][r] * awv[1]
                             + feat[mt][2][r] * awv[2] + feat[mt][3][r] * awv[3];
                    vv += __shfl_xor(vv, 1); vv += __shfl_xor(vv, 2);
                    vv += __shfl_xor(vv, 4); vv += __shfl_xor(vv, 8);
                    sp[mt][r] = vv;   // partial over this wave's 64 cols
                }
            if (l16 == 0) {
                #pragma unroll
                for (int mt = 0; mt < 4; ++mt)
                    #pragma unroll
                    for (int r = 0; r < 4; ++r)
                        scorep[cg * MROWS + 64 * rg + 16 * mt + 4 * q + r] = sp[mt][r];
            }
            __syncthreads();
            if (tid < MROWS) {
                float sc = scorep[tid] + scorep[MROWS + tid] + scorep[2 * MROWS + tid]
                         + scorep[3 * MROWS + tid] + attnb;
                float mo = m_lds[tid];
                float mn = fmaxf(mo, sc);
                float al = __expf(mo - mn);
                float pp = __expf(sc - mn);
                float ln = l_lds[tid] * al + pp;
                m_lds[tid] = mn; l_lds[tid] = ln;
                al_lds[tid] = al; pp_lds[tid] = pp;
                if (s == NNB - 1) il_lds[tid] = 1.f / ln;
            }
            __syncthreads();
            #pragma unroll
            for (int mt = 0; mt < 4; ++mt) {
                float alv[4], ppv[4];
                #pragma unroll
                for (int r = 0; r < 4; ++r) {
                    int rr = 64 * rg + 16 * mt + 4 * q + r;
                    alv[r] = al_lds[rr]; ppv[r] = pp_lds[rr];
                }
                #pragma unroll
                for (int ct = 0; ct < 4; ++ct)
                    #pragma unroll
                    for (int r = 0; r < 4; ++r)
                        agg[mt][ct][r] = agg[mt][ct][r] * alv[r] + ppv[r] * feat[mt][ct][r];
            }
        }
    }

    // ---- out = local_feat + agg / l  (nontemporal stores) ----
    #pragma unroll
    for (int mt = 0; mt < 4; ++mt)
        #pragma unroll
        for (int r = 0; r < 4; ++r) {
            int rr = 64 * rg + 16 * mt + 4 * q + r;
            float il = il_lds[rr];
            size_t base = (size_t)(row0 + rr) * DOUT + 64 * cg + l16;
            #pragma unroll
            for (int ct = 0; ct < 4; ++ct)
                __builtin_nontemporal_store(feat[mt][ct][r] + agg[mt][ct][r] * il,
                                            out + base + ct * 16);
        }
}

extern "C" void kernel_launch(void* const* d_in, const int* in_sizes, int n_in,
                              void* d_out, int out_size, void* d_ws, size_t ws_size,
                              hipStream_t stream) {
    const float* state = (const float*)d_in[0];
    const float* nbr   = (const float*)d_in[1];
    const float* gamma = (const float*)d_in[2];
    const float* beta  = (const float*)d_in[3];
    const float* W1    = (const float*)d_in[4];
    const float* b1    = (const float*)d_in[5];
    const float* W2    = (const float*)d_in[6];
    const float* b2    = (const float*)d_in[7];
    const float* aw    = (const float*)d_in[8];
    const float* ab    = (const float*)d_in[9];
    float* out = (float*)d_out;

    short* w1t = (short*)d_ws;               // [512][256] bf16, gamma-folded
    short* w2t = w1t + (size_t)DH * DIN;     // [256][512] bf16
    float* b1p = (float*)(w2t + (size_t)DOUT * DH);  // [512] fp32 (beta-folded)

    tcast_g<<<dim3(DH / 64, DIN / 64), 256, 0, stream>>>(W1, gamma, w1t, DIN, DH);
    tcast<<<dim3(DOUT / 64, DH / 64), 256, 0, stream>>>(W2, w2t, DH, DOUT);
    b1prep<<<2, 256, 0, stream>>>(W1, b1, beta, b1p);
    fused_node<<<BROWS / MROWS, 512, 0, stream>>>(state, nbr, b1p, b2, aw, ab,
                                                  w1t, w2t, out);
}